// Round 4
// baseline (51.039 us; speedup 1.0000x reference)
//
#include <hip/hip_runtime.h>

// Peg-solitaire batched env step, bitboard + global_load_lds edition.
// n = 262144 envs, one thread per env, EPB=256 envs/block.
//
// Inputs used: 0 pegs f32(n,33) | 1 n_pegs i32(n) | 2 done bool(n)
//              3 total_reward f32(n) | 4 actions i32(n)
// Inputs 5-10 (action tables, oob, i/j indices) are deterministic geometry
// from the reference's _constants(); hardcoded as constexpr below.
//
// Output flat f32 (184n): rewards[0,n) | states[n,148n) | done[148n,149n)
//  | pegs[149n,182n) | n_pegs[182n,183n) | total_reward[183n,184n)
//
// Bitboard: bit = i*7+j in a 7x7 grid, 33 valid holes (cross).
//   E = ~P & B;  feasible = OR over 4 dirs of P & shift(P,d) & shift(E,2d)
//   (column masks kill row wraparound for horizontal moves).

#define EPB 256
#define NTH 256

typedef float f32x4 __attribute__((ext_vector_type(4)));

__device__ __forceinline__ bool inboard(int i, int j) {
    return ((unsigned)i < 7u) && ((unsigned)j < 7u) &&
           (((i >= 2) && (i <= 4)) || ((j >= 2) && (j <= 4)));
}

// cell k -> bit (i*7+j). Cell order: (3,3) then row-major cross cells.
__device__ constexpr int C2B[33] = {
    24,  2,  3,  4,  9, 10, 11, 14, 15, 16, 17, 18, 19, 20,
    21, 22, 23, 25, 26, 27, 28, 29, 30, 31, 32, 33, 34,
    37, 38, 39, 44, 45, 46};
// bit -> cell (0 for off-board, matching reference p2i.get(..., 0))
__device__ constexpr unsigned char B2C[49] = {
    0, 0, 1, 2, 3, 0, 0,
    0, 0, 4, 5, 6, 0, 0,
    7, 8, 9,10,11,12,13,
   14,15,16, 0,17,18,19,
   20,21,22,23,24,25,26,
    0, 0,27,28,29, 0, 0,
    0, 0,30,31,32, 0, 0};

constexpr unsigned long long cross_mask() {
    unsigned long long b = 0;
    for (int i = 0; i < 7; ++i)
        for (int j = 0; j < 7; ++j)
            if ((i >= 2 && i <= 4) || (j >= 2 && j <= 4))
                b |= 1ull << (i * 7 + j);
    return b;
}
constexpr unsigned long long cols_le(int jmax) {
    unsigned long long b = 0;
    for (int i = 0; i < 7; ++i)
        for (int j = 0; j <= jmax; ++j) b |= 1ull << (i * 7 + j);
    return b;
}
constexpr unsigned long long cols_ge(int jmin) {
    unsigned long long b = 0;
    for (int i = 0; i < 7; ++i)
        for (int j = jmin; j < 7; ++j) b |= 1ull << (i * 7 + j);
    return b;
}
constexpr unsigned long long B_MASK = cross_mask();
constexpr unsigned long long C_LE4  = cols_le(4);   // sources of j+1 jumps
constexpr unsigned long long C_GE2  = cols_ge(2);   // sources of j-1 jumps

__global__ __launch_bounds__(NTH) void peg_step(
    const float* __restrict__ pegs_in,
    const int* __restrict__ n_pegs_in,
    const unsigned char* __restrict__ done_in,
    const float* __restrict__ tot_rew_in,
    const int* __restrict__ actions,
    float* __restrict__ out,
    int n)
{
    __shared__ __align__(16) float s_pegs[EPB * 33];   // 33.8 KB
    __shared__ unsigned long long s_bb[EPB];
    __shared__ float s_r1[EPB], s_r2[EPB];

    const int t  = threadIdx.x;
    const int e0 = blockIdx.x * EPB;
    const int e  = e0 + t;

    // ---- Stage pegs: async global->LDS, width 16, all issued back-to-back.
    // LDS dest per instr = wave-uniform base + lane*16 (linear) -> legal.
    {
        const char* src = (const char*)(pegs_in + (size_t)e0 * 33);
        char* dst = (char*)s_pegs;
        #pragma unroll
        for (int i = t; i < EPB * 33 / 4; i += NTH) {
            __builtin_amdgcn_global_load_lds(
                (const __attribute__((address_space(1))) void*)(src + 16 * (size_t)i),
                (__attribute__((address_space(3))) void*)(dst + 16 * (size_t)i),
                16, 0, 0);
        }
    }

    // ---- Scalar work that doesn't need LDS: overlap with staging latency.
    const int a         = actions[e];
    const int np_new    = n_pegs_in[e] - 1;
    const bool done_old = (done_in[e] != 0);
    const float tot     = tot_rew_in[e];

    const float rw  = (np_new == 1) ? 1.0f : (1.0f / 31.0f);
    const float npf = (float)np_new;
    out[e]                   = rw;          // rewards
    out[(size_t)182 * n + e] = npf;         // n_pegs
    out[(size_t)183 * n + e] = tot + rw;    // total_reward

    // Jump geometry from action id (pos_ids = repeat(arange(33),4)):
    const int p  = a >> 2;        // source cell
    const int mv = a & 3;         // move: [-1,0],[1,0],[0,-1],[0,1]
    const int pb = C2B[p];
    const int pi = pb / 7, pj = pb % 7;
    const int di = (mv == 0) ? -1 : (mv == 1) ? 1 : 0;
    const int dj = (mv == 2) ? -1 : (mv == 3) ? 1 : 0;
    const int db = di * 7 + dj;
    const bool mid_in = inboard(pi + di, pj + dj);
    const bool tgt_in = inboard(pi + 2 * di, pj + 2 * dj);
    const int mid_c = mid_in ? (int)B2C[pb + db]     : 0;  // p2i.get(mid, 0)
    const int tgt_c = tgt_in ? (int)B2C[pb + 2 * db] : 0;  // p2i.get(tgt, 0)

    __syncthreads();   // staging complete (barrier drains vmcnt)

    // ---- Apply jump to own LDS row (write order pos<-0, mid<-0, tgt<-1
    //      matters when OOB defaults alias cell 0), then build bitboard.
    float* row = s_pegs + t * 33;
    row[p]     = 0.0f;
    row[mid_c] = 0.0f;
    row[tgt_c] = 1.0f;

    unsigned long long P = 0;
    #pragma unroll
    for (int c = 0; c < 33; ++c)
        P |= (unsigned long long)(row[c] != 0.0f) << C2B[c];  // const shifts

    // ---- Feasibility over all 132 actions in ~15 wide ops
    const unsigned long long E = ~P & B_MASK;
    const unsigned long long feas =
        (P & (P >> 1) & (E >> 2)  & C_LE4) |   // j+1
        (P & (P << 1) & (E << 2)  & C_GE2) |   // j-1
        (P & (P >> 7) & (E >> 14))         |   // i+1
        (P & (P << 7) & (E << 14));            // i-1

    const bool dn = (np_new == 1) | done_old | (feas == 0ull);
    out[(size_t)148 * n + e] = dn ? 1.0f : 0.0f;    // done

    s_bb[t] = P;
    s_r1[t] = (npf - 1.0f)  * (1.0f / 31.0f);       // peg_ratio
    s_r2[t] = (32.0f - npf) * (1.0f / 31.0f);       // removed_ratio
    __syncthreads();

    // ---- pegs out: coalesced float4 from LDS, nontemporal
    {
        const f32x4* src = (const f32x4*)s_pegs;
        f32x4* dst = (f32x4*)(out + (size_t)149 * n + (size_t)e0 * 33);
        for (int i = t; i < EPB * 33 / 4; i += NTH)
            __builtin_nontemporal_store(src[i], dst + i);
    }

    // ---- states out: (env,7,7,3); el = rc*3+ch; ch0 = bit rc of bb,
    //      ch1/ch2 = ratios. All divisors compile-time (magic-mul).
    {
        f32x4* dst = (f32x4*)(out + (size_t)n + (size_t)e0 * 147);
        const int total = EPB * 147 / 4;             // 9408
        for (int q = t; q < total; q += NTH) {
            int f4  = q * 4;
            int env = f4 / 147;
            int el  = f4 - env * 147;
            unsigned long long bb = s_bb[env];
            float r1 = s_r1[env], r2 = s_r2[env];
            f32x4 v;
            #pragma unroll
            for (int r = 0; r < 4; ++r) {
                if (el == 147) {                     // env boundary
                    el = 0; ++env;
                    bb = s_bb[env]; r1 = s_r1[env]; r2 = s_r2[env];
                }
                int rc = el / 3;
                int ch = el - rc * 3;
                v[r] = (ch == 0) ? (float)((unsigned int)(bb >> rc) & 1u)
                                 : ((ch == 1) ? r1 : r2);
                ++el;
            }
            __builtin_nontemporal_store(v, dst + q);
        }
    }
}

extern "C" void kernel_launch(void* const* d_in, const int* in_sizes, int n_in,
                              void* d_out, int out_size, void* d_ws, size_t ws_size,
                              hipStream_t stream) {
    const float* pegs          = (const float*)d_in[0];
    const int* n_pegs          = (const int*)d_in[1];
    const unsigned char* done  = (const unsigned char*)d_in[2];
    const float* total_reward  = (const float*)d_in[3];
    const int* actions         = (const int*)d_in[4];
    // d_in[5..10]: action tables / oob / grid coords — hardcoded constexpr.
    float* out = (float*)d_out;

    int n = in_sizes[1];                    // 262144, divisible by EPB
    dim3 grid(n / EPB), block(NTH);
    hipLaunchKernelGGL(peg_step, grid, block, 0, stream,
                       pegs, n_pegs, done, total_reward, actions, out, n);
}

// Round 5
// 50.835 us; speedup vs baseline: 1.0040x; 1.0040x over previous
//
#include <hip/hip_runtime.h>

// Peg-solitaire batched env step, no-staging bitboard edition. n = 262144.
// One thread per env, EPB = NTH = 256.
//
// Key structure: pegs_out = pegs_in stream-copied (f4, starts writes early),
// then 3 cells patched per env after a barrier. Bitboard built from an own-row
// re-read (L1/L2-hot) with compile-time grid-bit shifts. No 33KB LDS staging.
//
// Inputs: 0 pegs f32(n,33) | 1 n_pegs i32(n) | 2 done bool(n)
//         3 total_reward f32(n) | 4 actions i32(n)
//         5 pos_ids(132) | 6 mid_idx(132) | 7 tgt_idx(132) (OOB->0 encoded)
//         8 oob (unused) | 9 i_ind(33) | 10 j_ind(33)
// Output flat f32 (184n): rewards[0,n) | states[n,148n) | done[148n,149n)
//  | pegs[149n,182n) | n_pegs[182n,183n) | total_reward[183n,184n)

#define EPB 256
#define NTH 256

typedef float f32x4 __attribute__((ext_vector_type(4)));

// cell k -> grid bit (i*7+j); used ONLY with compile-time indices (unrolled).
__device__ constexpr int C2B[33] = {
    24,  2,  3,  4,  9, 10, 11, 14, 15, 16, 17, 18, 19, 20,
    21, 22, 23, 25, 26, 27, 28, 29, 30, 31, 32, 33, 34,
    37, 38, 39, 44, 45, 46};

constexpr unsigned long long cross_mask() {
    unsigned long long b = 0;
    for (int i = 0; i < 7; ++i)
        for (int j = 0; j < 7; ++j)
            if ((i >= 2 && i <= 4) || (j >= 2 && j <= 4))
                b |= 1ull << (i * 7 + j);
    return b;
}
constexpr unsigned long long cols_le(int jmax) {
    unsigned long long b = 0;
    for (int i = 0; i < 7; ++i)
        for (int j = 0; j <= jmax; ++j) b |= 1ull << (i * 7 + j);
    return b;
}
constexpr unsigned long long cols_ge(int jmin) {
    unsigned long long b = 0;
    for (int i = 0; i < 7; ++i)
        for (int j = jmin; j < 7; ++j) b |= 1ull << (i * 7 + j);
    return b;
}
constexpr unsigned long long B_MASK = cross_mask();
constexpr unsigned long long C_LE4  = cols_le(4);   // sources of j+1 jumps
constexpr unsigned long long C_GE2  = cols_ge(2);   // sources of j-1 jumps

__global__ __launch_bounds__(NTH) void peg_step(
    const float* __restrict__ pegs_in,
    const int* __restrict__ n_pegs_in,
    const unsigned char* __restrict__ done_in,
    const float* __restrict__ tot_rew_in,
    const int* __restrict__ actions,
    const int* __restrict__ pos_ids,
    const int* __restrict__ mid_idx,
    const int* __restrict__ tgt_idx,
    const int* __restrict__ i_ind,
    const int* __restrict__ j_ind,
    float* __restrict__ out,
    int n)
{
    __shared__ int s_pos[132], s_mid[132], s_tgt[132];
    __shared__ int s_c2b[33];
    __shared__ unsigned long long s_bb[EPB];
    __shared__ float s_r1[EPB], s_r2[EPB];

    const int t  = threadIdx.x;
    const int e0 = blockIdx.x * EPB;
    const int e  = e0 + t;

    // ---- Phase 1a: stream-copy pegs_in -> pegs_out (coalesced f4).
    //      Starts the 35MB write stream immediately, overlapping reads.
    float* pegs_out = out + (size_t)149 * n;
    {
        const f32x4* src = (const f32x4*)(pegs_in + (size_t)e0 * 33);
        f32x4* dst = (f32x4*)(pegs_out + (size_t)e0 * 33);
        #pragma unroll
        for (int i = t; i < EPB * 33 / 4; i += NTH) dst[i] = src[i];
    }

    // ---- Phase 1b: own-row re-read (rows just touched by the copy -> L1/L2
    //      hot). Unrolled: all 33 loads in flight, const offsets.
    float rowv[33];
    {
        const float* row = pegs_in + (size_t)e * 33;
        #pragma unroll
        for (int c = 0; c < 33; ++c) rowv[c] = row[c];
    }

    // ---- Phase 1c: scalars + tables + early scalar outputs.
    const int a         = actions[e];
    const int np_new    = n_pegs_in[e] - 1;
    const bool done_old = (done_in[e] != 0);
    const float tot     = tot_rew_in[e];

    if (t < 132) { s_pos[t] = pos_ids[t]; s_mid[t] = mid_idx[t]; s_tgt[t] = tgt_idx[t]; }
    if (t < 33)  s_c2b[t] = i_ind[t] * 7 + j_ind[t];

    const float rw  = (np_new == 1) ? 1.0f : (1.0f / 31.0f);
    const float npf = (float)np_new;
    out[e]                   = rw;          // rewards
    out[(size_t)182 * n + e] = npf;         // n_pegs
    out[(size_t)183 * n + e] = tot + rw;    // total_reward

    __syncthreads();   // tables ready; copy-stores drained (orders the patch)

    // ---- Phase 2: bitboard from own row (compile-time shifts), apply jump,
    //      patch pegs_out, feasibility, done.
    unsigned long long P = 0;
    #pragma unroll
    for (int c = 0; c < 33; ++c)
        P |= (unsigned long long)(rowv[c] != 0.0f) << C2B[c];   // const shifts

    const int p = s_pos[a], m = s_mid[a], g = s_tgt[a];  // OOB -> 0 encoded
    const int bp = s_c2b[p], bm = s_c2b[m], bg = s_c2b[g];
    // order matters when OOB defaults alias cell 0: pos<-0, mid<-0, tgt<-1
    P &= ~(1ull << bp);
    P &= ~(1ull << bm);
    P |=  (1ull << bg);

    {   // patch the 3 cells (same thread, may-alias -> program order kept)
        float* od = pegs_out + (size_t)e * 33;
        od[p] = 0.0f;
        od[m] = 0.0f;
        od[g] = 1.0f;
    }

    const unsigned long long E = ~P & B_MASK;
    const unsigned long long feas =
        (P & (P >> 1) & (E >> 2)  & C_LE4) |   // j+1
        (P & (P << 1) & (E << 2)  & C_GE2) |   // j-1
        (P & (P >> 7) & (E >> 14))         |   // i+1
        (P & (P << 7) & (E << 14));            // i-1

    const bool dn = (np_new == 1) | done_old | (feas == 0ull);
    out[(size_t)148 * n + e] = dn ? 1.0f : 0.0f;    // done

    s_bb[t] = P;
    s_r1[t] = (npf - 1.0f)  * (1.0f / 31.0f);       // peg_ratio
    s_r2[t] = (32.0f - npf) * (1.0f / 31.0f);       // removed_ratio
    __syncthreads();

    // ---- Phase 3: states (env,7,7,3), coalesced f4, incremental rc/ch math.
    //      el = rc*3+ch; ch0 = grid bit rc; ch1/ch2 = ratios.
    {
        f32x4* dst = (f32x4*)(out + (size_t)n + (size_t)e0 * 147);
        const int total = EPB * 147 / 4;             // 9408
        for (int q = t; q < total; q += NTH) {
            const int f4  = q * 4;
            int env = f4 / 147;                      // magic-mul
            const int el = f4 - env * 147;
            int rc  = el / 3;                        // magic-mul (el < 147)
            int ch  = el - rc * 3;
            unsigned long long bb = s_bb[env];
            float r1 = s_r1[env], r2 = s_r2[env];
            f32x4 v;
            #pragma unroll
            for (int r = 0; r < 4; ++r) {
                v[r] = (ch == 0) ? (float)((unsigned int)(bb >> rc) & 1u)
                                 : ((ch == 1) ? r1 : r2);
                if (++ch == 3) {
                    ch = 0;
                    if (++rc == 49) {                // env boundary (<=1 per iter)
                        rc = 0; ++env;
                        bb = s_bb[env]; r1 = s_r1[env]; r2 = s_r2[env];
                    }
                }
            }
            dst[q] = v;
        }
    }
}

extern "C" void kernel_launch(void* const* d_in, const int* in_sizes, int n_in,
                              void* d_out, int out_size, void* d_ws, size_t ws_size,
                              hipStream_t stream) {
    const float* pegs          = (const float*)d_in[0];
    const int* n_pegs          = (const int*)d_in[1];
    const unsigned char* done  = (const unsigned char*)d_in[2];
    const float* total_reward  = (const float*)d_in[3];
    const int* actions         = (const int*)d_in[4];
    const int* pos_ids         = (const int*)d_in[5];
    const int* mid_idx         = (const int*)d_in[6];
    const int* tgt_idx         = (const int*)d_in[7];
    // d_in[8] oob_mask unused (tables already encode OOB->0)
    const int* i_ind           = (const int*)d_in[9];
    const int* j_ind           = (const int*)d_in[10];
    float* out = (float*)d_out;

    int n = in_sizes[1];                    // 262144, divisible by EPB
    dim3 grid(n / EPB), block(NTH);
    hipLaunchKernelGGL(peg_step, grid, block, 0, stream,
                       pegs, n_pegs, done, total_reward, actions,
                       pos_ids, mid_idx, tgt_idx, i_ind, j_ind, out, n);
}

// Round 6
// 44.538 us; speedup vs baseline: 1.1460x; 1.1414x over previous
//
#include <hip/hip_runtime.h>

// Peg-solitaire batched env step — per-WAVE pipeline edition. n = 262144.
// Each 64-lane wave owns 64 envs end-to-end; NO __syncthreads (no vmcnt
// drain, no cross-wave rendezvous). Intra-wave LDS visibility via
// s_waitcnt lgkmcnt(0) (wave lockstep + in-order DS completion).
//
// Inputs: 0 pegs f32(n,33) | 1 n_pegs i32(n) | 2 done bool(n)
//         3 total_reward f32(n) | 4 actions i32(n)
//         5 pos_ids(132) | 6 mid_idx(132) | 7 tgt_idx(132) (OOB->0 encoded)
//         8 oob (unused) | 9 i_ind(33) | 10 j_ind(33)
// Output flat f32 (184n): rewards[0,n) | states[n,148n) | done[148n,149n)
//  | pegs[149n,182n) | n_pegs[182n,183n) | total_reward[183n,184n)

#define NTH 256
#define WPB 4      // waves per block
#define EPW 64     // envs per wave

typedef float f32x4 __attribute__((ext_vector_type(4)));

// cell k -> grid bit (i*7+j); used ONLY with compile-time (unrolled) indices.
__device__ constexpr int C2B[33] = {
    24,  2,  3,  4,  9, 10, 11, 14, 15, 16, 17, 18, 19, 20,
    21, 22, 23, 25, 26, 27, 28, 29, 30, 31, 32, 33, 34,
    37, 38, 39, 44, 45, 46};

constexpr unsigned long long cross_mask() {
    unsigned long long b = 0;
    for (int i = 0; i < 7; ++i)
        for (int j = 0; j < 7; ++j)
            if ((i >= 2 && i <= 4) || (j >= 2 && j <= 4))
                b |= 1ull << (i * 7 + j);
    return b;
}
constexpr unsigned long long cols_le(int jmax) {
    unsigned long long b = 0;
    for (int i = 0; i < 7; ++i)
        for (int j = 0; j <= jmax; ++j) b |= 1ull << (i * 7 + j);
    return b;
}
constexpr unsigned long long cols_ge(int jmin) {
    unsigned long long b = 0;
    for (int i = 0; i < 7; ++i)
        for (int j = jmin; j < 7; ++j) b |= 1ull << (i * 7 + j);
    return b;
}
constexpr unsigned long long B_MASK = cross_mask();
constexpr unsigned long long C_LE4  = cols_le(4);   // sources of j+1 jumps
constexpr unsigned long long C_GE2  = cols_ge(2);   // sources of j-1 jumps

// Intra-wave LDS fence: all prior ds ops by this wave complete & visible.
__device__ __forceinline__ void wave_lds_fence() {
    asm volatile("s_waitcnt lgkmcnt(0)" ::: "memory");
    __builtin_amdgcn_sched_barrier(0);   // rule #18 insurance
}

__global__ __launch_bounds__(NTH) void peg_step(
    const float* __restrict__ pegs_in,
    const int* __restrict__ n_pegs_in,
    const unsigned char* __restrict__ done_in,
    const float* __restrict__ tot_rew_in,
    const int* __restrict__ actions,
    const int* __restrict__ pos_ids,
    const int* __restrict__ mid_idx,
    const int* __restrict__ tgt_idx,
    const int* __restrict__ i_ind,
    const int* __restrict__ j_ind,
    float* __restrict__ out,
    int n)
{
    __shared__ __align__(16) float s_pegs[WPB][EPW * 33];   // 33.8 KB
    __shared__ unsigned long long s_bb[WPB][EPW];
    __shared__ float s_r1[WPB][EPW], s_r2[WPB][EPW];

    const int t    = threadIdx.x;
    const int w    = t >> 6;
    const int lane = t & 63;
    const int ew0  = blockIdx.x * (WPB * EPW) + w * EPW;   // wave's first env
    const int e    = ew0 + lane;

    // ---- Phase A: stage this wave's 64 rows (8448 B contiguous) into its
    //      own LDS segment, coalesced f4 through VGPRs (R1-proven pattern).
    {
        const f32x4* src = (const f32x4*)(pegs_in + (size_t)ew0 * 33);
        f32x4* dst = (f32x4*)s_pegs[w];
        #pragma unroll
        for (int i = lane; i < EPW * 33 / 4; i += 64) dst[i] = src[i];
    }

    // ---- Per-env scalars + tiny L1-resident tables (overlap staging).
    const int a         = actions[e];
    const int np_new    = n_pegs_in[e] - 1;
    const bool done_old = (done_in[e] != 0);
    const float tot     = tot_rew_in[e];
    const int p = pos_ids[a], m = mid_idx[a], g = tgt_idx[a];   // OOB->0
    const int bp = i_ind[p] * 7 + j_ind[p];
    const int bm = i_ind[m] * 7 + j_ind[m];
    const int bg = i_ind[g] * 7 + j_ind[g];

    const float rw  = (np_new == 1) ? 1.0f : (1.0f / 31.0f);
    const float npf = (float)np_new;
    out[e]                   = rw;          // rewards
    out[(size_t)182 * n + e] = npf;         // n_pegs
    out[(size_t)183 * n + e] = tot + rw;    // total_reward

    wave_lds_fence();   // staged rows visible wave-wide

    // ---- Phase B: own-row bitboard (compile-time shifts), patch LDS + P.
    float* row = s_pegs[w] + lane * 33;
    unsigned long long P = 0;
    #pragma unroll
    for (int c = 0; c < 33; ++c)
        P |= (unsigned long long)(row[c] != 0.0f) << C2B[c];

    // write order pos<-0, mid<-0, tgt<-1 (aliasing when OOB defaults to 0)
    row[p] = 0.0f;
    row[m] = 0.0f;
    row[g] = 1.0f;
    P &= ~(1ull << bp);
    P &= ~(1ull << bm);
    P |=  (1ull << bg);

    // ---- Feasibility over all 132 actions in ~15 wide ops
    const unsigned long long E = ~P & B_MASK;
    const unsigned long long feas =
        (P & (P >> 1) & (E >> 2)  & C_LE4) |   // j+1
        (P & (P << 1) & (E << 2)  & C_GE2) |   // j-1
        (P & (P >> 7) & (E >> 14))         |   // i+1
        (P & (P << 7) & (E << 14));            // i-1

    const bool dn = (np_new == 1) | done_old | (feas == 0ull);
    out[(size_t)148 * n + e] = dn ? 1.0f : 0.0f;    // done

    s_bb[w][lane] = P;
    s_r1[w][lane] = (npf - 1.0f)  * (1.0f / 31.0f);   // peg_ratio
    s_r2[w][lane] = (32.0f - npf) * (1.0f / 31.0f);   // removed_ratio

    wave_lds_fence();   // patches + bb/ratios visible wave-wide

    // ---- Phase C: stream pegs out (coalesced f4 from this wave's segment).
    {
        const f32x4* src = (const f32x4*)s_pegs[w];
        f32x4* dst = (f32x4*)(out + (size_t)149 * n + (size_t)ew0 * 33);
        #pragma unroll
        for (int i = lane; i < EPW * 33 / 4; i += 64) dst[i] = src[i];
    }

    // ---- Phase D: states (env,7,7,3) for this wave's 64 envs, coalesced f4.
    //      el = rc*3+ch; ch0 = grid bit rc of bb; ch1/ch2 = ratios.
    {
        f32x4* dst = (f32x4*)(out + (size_t)n + (size_t)ew0 * 147);
        const int total = EPW * 147 / 4;              // 2352
        for (int q = lane; q < total; q += 64) {
            const int f4 = q * 4;
            int env = f4 / 147;                       // magic-mul
            int el  = f4 - env * 147;
            unsigned long long bb = s_bb[w][env];
            float r1 = s_r1[w][env], r2 = s_r2[w][env];
            f32x4 v;
            #pragma unroll
            for (int r = 0; r < 4; ++r) {
                if (el == 147) {                      // env boundary
                    el = 0; ++env;
                    bb = s_bb[w][env]; r1 = s_r1[w][env]; r2 = s_r2[w][env];
                }
                const int rc = el / 3;                // magic-mul
                const int ch = el - rc * 3;
                v[r] = (ch == 0) ? (float)((unsigned int)(bb >> rc) & 1u)
                                 : ((ch == 1) ? r1 : r2);
                ++el;
            }
            dst[q] = v;
        }
    }
}

extern "C" void kernel_launch(void* const* d_in, const int* in_sizes, int n_in,
                              void* d_out, int out_size, void* d_ws, size_t ws_size,
                              hipStream_t stream) {
    const float* pegs          = (const float*)d_in[0];
    const int* n_pegs          = (const int*)d_in[1];
    const unsigned char* done  = (const unsigned char*)d_in[2];
    const float* total_reward  = (const float*)d_in[3];
    const int* actions         = (const int*)d_in[4];
    const int* pos_ids         = (const int*)d_in[5];
    const int* mid_idx         = (const int*)d_in[6];
    const int* tgt_idx         = (const int*)d_in[7];
    // d_in[8] oob_mask unused (tables already encode OOB->0)
    const int* i_ind           = (const int*)d_in[9];
    const int* j_ind           = (const int*)d_in[10];
    float* out = (float*)d_out;

    int n = in_sizes[1];                    // 262144, divisible by 256
    dim3 grid(n / (WPB * EPW)), block(NTH);
    hipLaunchKernelGGL(peg_step, grid, block, 0, stream,
                       pegs, n_pegs, done, total_reward, actions,
                       pos_ids, mid_idx, tgt_idx, i_ind, j_ind, out, n);
}